// Round 13
// baseline (633.841 us; speedup 1.0000x reference)
//
#include <hip/hip_runtime.h>
#include <hip/hip_cooperative_groups.h>

#define EPS_BN 1e-5f
typedef float v2f __attribute__((ext_vector_type(2)));
namespace cg = cooperative_groups;

struct LayerDesc {
    const float* W; const float* b; const float* bn;
    float* wt; float* shb; int O; int C;
};

struct MegaArgs {
    LayerDesc l[6];
    const float *a2w, *a2b, *w3, *b3, *bn3; float *w3c, *sh3;
    const float *a1w, *a1b, *w5, *b5, *bn5; float *w5c, *sh5;
    const float *xyz0, *xyz1, *xyz2;
    int* idx1; float* wgt1; int* idx2; float* wgt2;
    const float *x, *mask, *sa0, *sa1;
    const float *wout, *bout;
    float *wt1, *sb1, *wt2, *sb2, *wt3, *sb3, *wt4, *sb4, *wt5, *sb5, *wt6, *sb6;
    float *base1, *base3, *slotA, *slotB, *outp;
};

// ---------------- conv on one wave: wave-private LDS weights, no barriers ----
template <int CT, int O, int OT, bool RELU, int ADD>
__device__ __forceinline__ void conv_wave(
    int nt, int ot, int nb, int lane,
    const float* __restrict__ src0, int qdiv0,
    const float* __restrict__ Wt, const float* __restrict__ shb,
    const float* __restrict__ basep, int qdivb,
    float* __restrict__ outp, int N, float* wlds)
{
    static_assert(OT % 4 == 0, "OT grouping");
    static_assert(CT % 8 == 0 || CT % 8 == 4, "CT tail");
    const int oBase = ot * OT;
    const int n0 = (nt * 64 + lane) * 4;

    __builtin_amdgcn_wave_barrier();
    for (int i = lane; i < CT * OT; i += 64)
        wlds[i] = Wt[(size_t)(i / OT) * O + oBase + (i % OT)];
    __builtin_amdgcn_wave_barrier();

    const float* s0 = src0 + (size_t)(nb / qdiv0) * CT * N + n0;

    v2f acc[OT][2];
#pragma unroll
    for (int ol = 0; ol < OT; ++ol) { acc[ol][0] = (v2f)0.f; acc[ol][1] = (v2f)0.f; }

    auto loadrow = [&](float (&xv)[4], int c) {
        float4 t = *reinterpret_cast<const float4*>(s0 + (size_t)c * N);
        xv[0] = t.x; xv[1] = t.y; xv[2] = t.z; xv[3] = t.w;
    };
    auto comprow = [&](const float (&xv)[4], int c) {
        v2f x01; x01[0] = xv[0]; x01[1] = xv[1];
        v2f x23; x23[0] = xv[2]; x23[1] = xv[3];
#pragma unroll
        for (int g = 0; g < OT / 4; ++g) {
            float4 wv = *reinterpret_cast<const float4*>(&wlds[c * OT + g * 4]);
            float ww[4] = {wv.x, wv.y, wv.z, wv.w};
#pragma unroll
            for (int r = 0; r < 4; ++r) {
                v2f w2; w2[0] = ww[r]; w2[1] = ww[r];
                acc[g * 4 + r][0] = __builtin_elementwise_fma(w2, x01, acc[g * 4 + r][0]);
                acc[g * 4 + r][1] = __builtin_elementwise_fma(w2, x23, acc[g * 4 + r][1]);
            }
        }
    };
    auto loadg = [&](float (&buf)[4][4], int c) {
#pragma unroll
        for (int q = 0; q < 4; ++q) loadrow(buf[q], c + q);
    };
    auto compg = [&](const float (&buf)[4][4], int c) {
#pragma unroll
        for (int q = 0; q < 4; ++q) comprow(buf[q], c + q);
    };

    {
        float xa[4][4], xb[4][4];
        loadg(xa, 0); loadg(xb, 4);
        int c = 0;
#pragma unroll 1
        for (; c + 16 <= CT; c += 8) {
            compg(xa, c);     loadg(xa, c + 8);
            compg(xb, c + 4); loadg(xb, c + 12);
        }
        compg(xa, c);
        if constexpr (CT % 8 == 4) {
            loadg(xa, c + 8);
            compg(xb, c + 4);
            compg(xa, c + 8);
        } else {
            compg(xb, c + 4);
        }
    }

    const float* bp = (ADD == 2) ? (basep + ((size_t)(nb / qdivb) * O + oBase) * N + n0) : nullptr;
#pragma unroll
    for (int ol = 0; ol < OT; ++ol) {
        int o = oBase + ol;
        float addv[4];
        if constexpr (ADD == 2) {
            float4 t = *reinterpret_cast<const float4*>(bp + (size_t)ol * N);
            addv[0] = t.x; addv[1] = t.y; addv[2] = t.z; addv[3] = t.w;
        } else if constexpr (ADD == 1) {
            float sb = shb[o];
#pragma unroll
            for (int j = 0; j < 4; ++j) addv[j] = sb;
        } else {
#pragma unroll
            for (int j = 0; j < 4; ++j) addv[j] = 0.f;
        }
        float res[4];
#pragma unroll
        for (int j = 0; j < 4; ++j) {
            float y = acc[ol][j >> 1][j & 1] + addv[j];
            if constexpr (RELU) y = fmaxf(y, 0.f);
            res[j] = y;
        }
        float4 t; t.x = res[0]; t.y = res[1]; t.z = res[2]; t.w = res[3];
        *reinterpret_cast<float4*>(outp + ((size_t)nb * O + o) * N + n0) = t;
    }
}

// ---------------- stage 0: prep (transpose + fold BN) + composites ----------
__device__ void stage_prep(const MegaArgs& a, int bx, int tid) {
    if (bx < 96) {
        LayerDesc d = a.l[bx / 16];
        int sub = bx % 16;
        int total = d.O * d.C;
        for (int i = sub * 256 + tid; i < total; i += 16 * 256) {
            int c = i / d.O, o = i - (i / d.O) * d.O;
            float sc = 1.f;
            if (d.bn) { float g = d.bn[o], v = d.bn[3 * d.O + o]; sc = g * rsqrtf(v + EPS_BN); }
            d.wt[i] = d.W[(size_t)o * d.C + c] * sc;
        }
        for (int o = sub * 256 + tid; o < d.O; o += 16 * 256) {
            float sc = 1.f, sh = 0.f;
            if (d.bn) {
                float g = d.bn[o], be = d.bn[d.O + o], m = d.bn[2 * d.O + o], v = d.bn[3 * d.O + o];
                sc = g * rsqrtf(v + EPS_BN); sh = be - m * sc;
            }
            d.shb[o] = d.b[o] * sc + sh;
        }
    } else if (bx < 169) {
        int e = (bx - 96) * 256 + tid;
        if (e < 128 * 144) {
            int k = e / 144, o = e - (e / 144) * 144;
            float sc = a.bn3[o] * rsqrtf(a.bn3[3 * 144 + o] + EPS_BN);
            float s = 0.f;
            for (int c = 0; c < 144; ++c)
                s += a.a2w[c * 128 + k] * a.w3[(size_t)o * 288 + 144 + c];
            a.w3c[k * 144 + o] = s * sc;
        } else if (e < 128 * 144 + 144) {
            int o = e - 128 * 144;
            float g = a.bn3[o], be = a.bn3[144 + o], m = a.bn3[2 * 144 + o], v = a.bn3[3 * 144 + o];
            float sc = g * rsqrtf(v + EPS_BN);
            float s = 0.f;
            for (int c = 0; c < 144; ++c) s += a.w3[(size_t)o * 288 + 144 + c] * a.a2b[c];
            a.sh3[o] = (s + a.b3[o] - m) * sc + be;
        }
    } else if (bx < 171) {
        int e = (bx - 169) * 256 + tid;
        if (e < 3 * 72) {
            int k = e / 72, o = e - (e / 72) * 72;
            float sc = a.bn5[o] * rsqrtf(a.bn5[3 * 72 + o] + EPS_BN);
            float s = 0.f;
            for (int c = 0; c < 72; ++c)
                s += a.a1w[c * 3 + k] * a.w5[(size_t)o * 144 + 72 + c];
            a.w5c[k * 72 + o] = s * sc;
        } else if (e < 3 * 72 + 72) {
            int o = e - 3 * 72;
            float g = a.bn5[o], be = a.bn5[72 + o], m = a.bn5[2 * 72 + o], v = a.bn5[3 * 72 + o];
            float sc = g * rsqrtf(v + EPS_BN);
            float s = 0.f;
            for (int c = 0; c < 72; ++c) s += a.w5[(size_t)o * 144 + 72 + c] * a.a1b[c];
            a.sh5[o] = (s + a.b5[o] - m) * sc + be;
        }
    }
}

// ---------------- three_nn: one 256-thread block per 32 unknowns ------------
__device__ void three_nn_block(const MegaArgs& a, int t, int tid, float* smem) {
    float* kl = smem;                 // 3072
    float* sd = smem + 3072;          // 768
    int*   si = (int*)(smem + 3840);  // 768
    const float *unknown, *known; int Nu, Nk, blk, b; int* idx; float* wgt;
    if (t < 64) {
        unknown = a.xyz1; known = a.xyz2; Nu = 1024; Nk = 256;
        b = t >> 5; blk = t & 31; idx = a.idx1; wgt = a.wgt1;
    } else {
        t -= 64;
        unknown = a.xyz0; known = a.xyz1; Nu = 4096; Nk = 1024;
        b = t >> 7; blk = t & 127; idx = a.idx2; wgt = a.wgt2;
    }
    for (int i = tid; i < Nk * 3; i += 256) kl[i] = known[(size_t)b * Nk * 3 + i];
    __syncthreads();
    const int u = tid & 31, seg = tid >> 5;
    const int n = blk * 32 + u;
    const float* up = unknown + ((size_t)b * Nu + n) * 3;
    const float ux = up[0], uy = up[1], uz = up[2];
    float d0 = 1e30f, d1 = 1e30f, d2 = 1e30f;
    int i0 = 0, i1 = 0, i2 = 0;
    const int span = Nk >> 3;
    const int klo = seg * span, khi = klo + span;
    for (int k = klo; k < khi; ++k) {
        float dx = __fsub_rn(ux, kl[3 * k + 0]);
        float dy = __fsub_rn(uy, kl[3 * k + 1]);
        float dz = __fsub_rn(uz, kl[3 * k + 2]);
        float d = __fadd_rn(__fadd_rn(__fmul_rn(dx, dx), __fmul_rn(dy, dy)), __fmul_rn(dz, dz));
        if (d < d0)      { d2 = d1; i2 = i1; d1 = d0; i1 = i0; d0 = d; i0 = k; }
        else if (d < d1) { d2 = d1; i2 = i1; d1 = d;  i1 = k; }
        else if (d < d2) { d2 = d;  i2 = k; }
    }
    int bs = (seg * 32 + u) * 3;
    sd[bs] = d0; sd[bs + 1] = d1; sd[bs + 2] = d2;
    si[bs] = i0; si[bs + 1] = i1; si[bs + 2] = i2;
    __syncthreads();
    if (tid < 32) {
        float m0 = 1e30f, m1 = 1e30f, m2 = 1e30f;
        int j0 = 0, j1 = 0, j2 = 0;
        for (int s = 0; s < 8; ++s)
            for (int c = 0; c < 3; ++c) {
                float d = sd[(s * 32 + u) * 3 + c];
                int ii = si[(s * 32 + u) * 3 + c];
                if (d < m0)      { m2 = m1; j2 = j1; m1 = m0; j1 = j0; m0 = d; j0 = ii; }
                else if (d < m1) { m2 = m1; j2 = j1; m1 = d;  j1 = ii; }
                else if (d < m2) { m2 = d;  j2 = ii; }
            }
        float w0 = 1.f / (m0 + 1e-8f), w1 = 1.f / (m1 + 1e-8f), w2 = 1.f / (m2 + 1e-8f);
        float s = w0 + w1 + w2;
        size_t base = ((size_t)b * Nu + n) * 3;
        idx[base + 0] = j0; idx[base + 1] = j1; idx[base + 2] = j2;
        wgt[base + 0] = w0 / s; wgt[base + 1] = w1 / s; wgt[base + 2] = w2 / s;
    }
}

// ---------------- stage 1: 3nn (blocks 0..319) + bases (waves on 320..511) --
__device__ void stage_nn_bases(const MegaArgs& a, int bx, int tid, float* smem) {
    if (bx < 320) { three_nn_block(a, bx, tid, smem); return; }
    int wid = tid >> 6, lane = tid & 63;
    float* wlds = smem + wid * 2048;
    int t = (bx - 320) * 4 + wid;
    if (t < 148) {
        conv_wave<288, 296, 4, false, 1>(0, t % 74, t / 74, lane,
            a.x, 1, a.wt1, a.sb1, nullptr, 1, a.base1, 256, wlds);
    } else if (t < 436) {
        int u = t - 148;
        conv_wave<128, 144, 4, false, 1>(u % 4, (u / 4) % 36, u / 144, lane,
            a.sa1, 1, a.w3c, a.sh3, nullptr, 1, a.base3, 1024, wlds);
    }
}

__device__ void stage_h1(const MegaArgs& a, int gw, int lane, float* wlds) {
    if (gw >= 1184) return;
    conv_wave<8, 296, 8, true, 2>(0, gw % 37, gw / 37, lane,
        a.mask, 1, a.wt1 + 288 * 296, a.sb1, a.base1, 16, a.slotA, 256, wlds);
}
__device__ void stage_h2(const MegaArgs& a, int gw, int lane, float* wlds) {
    if (gw >= 1152) return;
    conv_wave<296, 144, 4, true, 1>(0, gw % 36, gw / 36, lane,
        a.slotA, 1, a.wt2, a.sb2, nullptr, 1, a.slotB, 256, wlds);
}
__device__ void stage_g3(const MegaArgs& a, int gw, int lane, float* wlds) {
    if (gw >= 1152) return;
    conv_wave<144, 144, 4, false, 0>(0, gw % 36, gw / 36, lane,
        a.slotB, 1, a.wt3, a.sb3, nullptr, 1, a.slotA, 256, wlds);
}
__device__ void stage_gather1(const MegaArgs& a, int gw, int lane, float* wlds) {
    if (gw >= 512) return;
    int nb = gw >> 4, nt = gw & 15;
    int n = nt * 64 + lane;
    int b = nb >> 4;
    size_t nnb = ((size_t)b * 1024 + n) * 3;
    int j0 = a.idx1[nnb], j1 = a.idx1[nnb + 1], j2 = a.idx1[nnb + 2];
    float w0 = a.wgt1[nnb], w1 = a.wgt1[nnb + 1], w2 = a.wgt1[nnb + 2];
    const float* fbase = a.slotA + (size_t)nb * 144 * 256;
    float* obase = a.slotB + (size_t)nb * 144 * 1024 + n;
    const float* bbase = a.base3 + (size_t)b * 144 * 1024 + n;
    for (int cc = 0; cc < 144; cc += 8) {
        __builtin_amdgcn_wave_barrier();
        const float4* src = reinterpret_cast<const float4*>(fbase + (size_t)cc * 256);
        float4* dst = reinterpret_cast<float4*>(wlds);
        for (int i = lane; i < 512; i += 64) dst[i] = src[i];
        __builtin_amdgcn_wave_barrier();
#pragma unroll
        for (int r = 0; r < 8; ++r) {
            const float* rp = wlds + r * 256;
            float v = w0 * rp[j0] + w1 * rp[j1] + w2 * rp[j2] + bbase[(size_t)(cc + r) * 1024];
            obase[(size_t)(cc + r) * 1024] = fmaxf(v, 0.f);
        }
    }
}
__device__ void stage_h4(const MegaArgs& a, int gw, int lane, float* wlds) {
    for (int t = gw; t < 2304; t += 2048)
        conv_wave<144, 72, 4, true, 1>((t / 18) % 4, t % 18, t / 72, lane,
            a.slotB, 1, a.wt4, a.sb4, nullptr, 1, a.slotA, 1024, wlds);
}
__device__ void stage_g5(const MegaArgs& a, int gw, int lane, float* wlds) {
    for (int t = gw; t < 2304; t += 2048)
        conv_wave<72, 72, 4, false, 0>((t / 18) % 4, t % 18, t / 72, lane,
            a.slotA, 1, a.wt5, a.sb5, nullptr, 1, a.slotB, 1024, wlds);
}
// stage 8: fused gather2 + base5(on-the-fly) + h6 + out
__device__ void stage_h6out(const MegaArgs& a, int bx, int tid, float* smem) {
    float* wl   = smem;            // 72*36
    float* w5l  = smem + 2592;     // 216
    float* sh5l = smem + 2808;     // 72
    float* owv  = smem + 2880;     // 36
    float* sh6l = smem + 2916;     // 36
    for (int i = tid; i < 2592; i += 256) wl[i] = a.wt6[i];
    if (tid < 216) w5l[tid] = a.w5c[tid];
    if (tid < 72) sh5l[tid] = a.sh5[tid];
    if (tid < 36) { owv[tid] = a.wout[tid]; sh6l[tid] = a.sb6[tid]; }
    __syncthreads();
    int gw = bx * 4 + (tid >> 6), lane = tid & 63;
    int nb = gw >> 6, nt = gw & 63;
    int n = nt * 64 + lane;
    int b = nb >> 4;
    size_t nn = ((size_t)b * 4096 + n) * 3;
    int j0 = a.idx2[nn], j1 = a.idx2[nn + 1], j2 = a.idx2[nn + 2];
    float w0 = a.wgt2[nn], w1 = a.wgt2[nn + 1], w2 = a.wgt2[nn + 2];
    const float* gb = a.slotB + (size_t)nb * 72 * 1024;
    const float* s0 = a.sa0 + (size_t)b * 3 * 4096 + n;
    float sx = s0[0], sy = s0[4096], sz = s0[8192];

    v2f acc[18];
#pragma unroll
    for (int o = 0; o < 18; ++o) acc[o] = (v2f)0.f;

    float ra[4][3], rb[4][3];
    auto ld = [&](float (&r)[4][3], int c) {
#pragma unroll
        for (int q = 0; q < 4; ++q) {
            const float* rp = gb + (size_t)(c + q) * 1024;
            r[q][0] = rp[j0]; r[q][1] = rp[j1]; r[q][2] = rp[j2];
        }
    };
    auto cp = [&](const float (&r)[4][3], int c) {
#pragma unroll
        for (int q = 0; q < 4; ++q) {
            int cc = c + q;
            float base = w5l[cc] * sx + w5l[72 + cc] * sy + w5l[144 + cc] * sz + sh5l[cc];
            float xv = fmaxf(w0 * r[q][0] + w1 * r[q][1] + w2 * r[q][2] + base, 0.f);
            v2f xv2; xv2[0] = xv; xv2[1] = xv;
#pragma unroll
            for (int g = 0; g < 9; ++g) {
                float4 wv = *reinterpret_cast<const float4*>(&wl[cc * 36 + g * 4]);
                v2f wa; wa[0] = wv.x; wa[1] = wv.y;
                v2f wb; wb[0] = wv.z; wb[1] = wv.w;
                acc[g * 2 + 0] = __builtin_elementwise_fma(wa, xv2, acc[g * 2 + 0]);
                acc[g * 2 + 1] = __builtin_elementwise_fma(wb, xv2, acc[g * 2 + 1]);
            }
        }
    };
    ld(ra, 0); ld(rb, 4);
    int c = 0;
#pragma unroll 1
    for (; c + 16 <= 72; c += 8) {
        cp(ra, c);     ld(ra, c + 8);
        cp(rb, c + 4); ld(rb, c + 12);
    }
    cp(ra, c); cp(rb, c + 4);

    float r = a.bout[0];
#pragma unroll
    for (int o = 0; o < 36; ++o) r += owv[o] * fmaxf(acc[o >> 1][o & 1] + sh6l[o], 0.f);
    a.outp[(size_t)nb * 4096 + n] = r;
}

template <int S>
__device__ __forceinline__ void run_stage(const MegaArgs& a, int bx, int tid, float* smem) {
    int wid = tid >> 6, lane = tid & 63;
    int gw = bx * 4 + wid;
    float* wlds = smem + wid * 2048;
    if constexpr (S == 0) stage_prep(a, bx, tid);
    else if constexpr (S == 1) stage_nn_bases(a, bx, tid, smem);
    else if constexpr (S == 2) stage_h1(a, gw, lane, wlds);
    else if constexpr (S == 3) stage_h2(a, gw, lane, wlds);
    else if constexpr (S == 4) stage_g3(a, gw, lane, wlds);
    else if constexpr (S == 5) stage_gather1(a, gw, lane, wlds);
    else if constexpr (S == 6) stage_h4(a, gw, lane, wlds);
    else if constexpr (S == 7) stage_g5(a, gw, lane, wlds);
    else stage_h6out(a, bx, tid, smem);
}

__global__ __launch_bounds__(256, 2) void mega_kernel(MegaArgs a) {
    cg::grid_group grid = cg::this_grid();
    __shared__ __align__(16) float smem[8192];
    const int bx = blockIdx.x, tid = threadIdx.x;
    run_stage<0>(a, bx, tid, smem); grid.sync();
    run_stage<1>(a, bx, tid, smem); grid.sync();
    run_stage<2>(a, bx, tid, smem); grid.sync();
    run_stage<3>(a, bx, tid, smem); grid.sync();
    run_stage<4>(a, bx, tid, smem); grid.sync();
    run_stage<5>(a, bx, tid, smem); grid.sync();
    run_stage<6>(a, bx, tid, smem); grid.sync();
    run_stage<7>(a, bx, tid, smem); grid.sync();
    run_stage<8>(a, bx, tid, smem);
}

template <int S>
__global__ __launch_bounds__(256, 2) void stage_kernel(MegaArgs a) {
    __shared__ __align__(16) float smem[8192];
    run_stage<S>(a, blockIdx.x, threadIdx.x, smem);
}

extern "C" void kernel_launch(void* const* d_in, const int* in_sizes, int n_in,
                              void* d_out, int out_size, void* d_ws, size_t ws_size,
                              hipStream_t stream) {
    const int B = 2, N0 = 4096, N1 = 1024, N2 = 256;
    const int I1 = 144;
    const int NB = 32;

    float* ws = (float*)d_ws;
    size_t off = 0;
    auto alloc = [&](size_t n) { size_t p = off; off += (n + 15) & ~(size_t)15; return p; };

    size_t wgt1  = alloc((size_t)B * N1 * 3);
    size_t wgt2  = alloc((size_t)B * N0 * 3);
    size_t idx1  = alloc((size_t)B * N1 * 3);
    size_t idx2  = alloc((size_t)B * N0 * 3);
    size_t slotA = alloc((size_t)NB * 296 * N2);  // h1 / g3 / h4
    size_t slotB = alloc((size_t)NB * I1 * N1);   // h2 / h3 / g5
    size_t base1 = alloc((size_t)B * 296 * N2);
    size_t base3 = alloc((size_t)B * I1 * N1);
    size_t wt1 = alloc(296 * 296), sb1 = alloc(296);
    size_t wt2 = alloc(296 * 144), sb2 = alloc(144);
    size_t wt3 = alloc(288 * 144), sb3 = alloc(144);
    size_t wt4 = alloc(144 * 72),  sb4 = alloc(72);
    size_t wt5 = alloc(144 * 72),  sb5 = alloc(72);
    size_t wt6 = alloc(72 * 36),   sb6 = alloc(36);
    size_t w3c = alloc(128 * 144), sh3 = alloc(144);
    size_t w5c = alloc(3 * 72),    sh5 = alloc(72);
    (void)ws_size; (void)in_sizes; (void)n_in;

    auto din = [&](int i) { return (const float*)d_in[i]; };

    MegaArgs ma;
    ma.l[0] = { din(7),  din(8),  din(9),  ws + wt1, ws + sb1, 296, 296 };
    ma.l[1] = { din(10), din(11), din(12), ws + wt2, ws + sb2, 144, 296 };
    ma.l[2] = { din(17), din(18), din(19), ws + wt3, ws + sb3, 144, 288 };
    ma.l[3] = { din(20), din(21), din(22), ws + wt4, ws + sb4, 72, 144 };
    ma.l[4] = { din(23), din(24), din(25), ws + wt5, ws + sb5, 72, 144 };
    ma.l[5] = { din(26), din(27), din(28), ws + wt6, ws + sb6, 36, 72 };
    ma.a2w = din(15); ma.a2b = din(16); ma.w3 = din(17); ma.b3 = din(18); ma.bn3 = din(19);
    ma.w3c = ws + w3c; ma.sh3 = ws + sh3;
    ma.a1w = din(13); ma.a1b = din(14); ma.w5 = din(23); ma.b5 = din(24); ma.bn5 = din(25);
    ma.w5c = ws + w5c; ma.sh5 = ws + sh5;
    ma.xyz0 = din(4); ma.xyz1 = din(5); ma.xyz2 = din(6);
    ma.idx1 = (int*)(ws + idx1); ma.wgt1 = ws + wgt1;
    ma.idx2 = (int*)(ws + idx2); ma.wgt2 = ws + wgt2;
    ma.x = din(0); ma.mask = din(1); ma.sa0 = din(2); ma.sa1 = din(3);
    ma.wout = din(29); ma.bout = din(30);
    ma.wt1 = ws + wt1; ma.sb1 = ws + sb1; ma.wt2 = ws + wt2; ma.sb2 = ws + sb2;
    ma.wt3 = ws + wt3; ma.sb3 = ws + sb3; ma.wt4 = ws + wt4; ma.sb4 = ws + sb4;
    ma.wt5 = ws + wt5; ma.sb5 = ws + sb5; ma.wt6 = ws + wt6; ma.sb6 = ws + sb6;
    ma.base1 = ws + base1; ma.base3 = ws + base3;
    ma.slotA = ws + slotA; ma.slotB = ws + slotB;
    ma.outp = (float*)d_out;

    void* kargs[] = { (void*)&ma };
    hipError_t e = hipLaunchCooperativeKernel((const void*)mega_kernel,
                                              dim3(512), dim3(256), kargs, 0, stream);
    if (e != hipSuccess) {
        (void)hipGetLastError();
        stage_kernel<0><<<dim3(512), 256, 0, stream>>>(ma);
        stage_kernel<1><<<dim3(512), 256, 0, stream>>>(ma);
        stage_kernel<2><<<dim3(512), 256, 0, stream>>>(ma);
        stage_kernel<3><<<dim3(512), 256, 0, stream>>>(ma);
        stage_kernel<4><<<dim3(512), 256, 0, stream>>>(ma);
        stage_kernel<5><<<dim3(512), 256, 0, stream>>>(ma);
        stage_kernel<6><<<dim3(512), 256, 0, stream>>>(ma);
        stage_kernel<7><<<dim3(512), 256, 0, stream>>>(ma);
        stage_kernel<8><<<dim3(512), 256, 0, stream>>>(ma);
    }
}

// Round 14
// 174.447 us; speedup vs baseline: 3.6334x; 3.6334x over previous
//
#include <hip/hip_runtime.h>

#define EPS_BN 1e-5f
typedef float v2f __attribute__((ext_vector_type(2)));

// ---------------- prep/compose + three_nn merged (r11-verified) ----------
struct LayerDesc {
    const float* W; const float* b; const float* bn;
    float* wt; float* shb; int O; int C;
};
struct HeadArgs {
    LayerDesc l[6];
    const float* a2w; const float* a2b; const float* w3; const float* b3; const float* bn3;
    float* w3c; float* sh3;
    const float* a1w; const float* a1b; const float* w5; const float* b5; const float* bn5;
    float* w5c; float* sh5;
    const float* xyz0; const float* xyz1; const float* xyz2;
    int* idx1; float* wgt1; int* idx2; float* wgt2;
};

__global__ __launch_bounds__(256) void head_kernel(HeadArgs a) {
    const int bx = blockIdx.x, tid = threadIdx.x;
    if (bx < 96) {
        LayerDesc d = a.l[bx / 16];
        int sub = bx % 16;
        int total = d.O * d.C;
        for (int i = sub * 256 + tid; i < total; i += 16 * 256) {
            int c = i / d.O, o = i - (i / d.O) * d.O;
            float sc = 1.f;
            if (d.bn) { float g = d.bn[o], v = d.bn[3 * d.O + o]; sc = g * rsqrtf(v + EPS_BN); }
            d.wt[i] = d.W[(size_t)o * d.C + c] * sc;
        }
        for (int o = sub * 256 + tid; o < d.O; o += 16 * 256) {
            float sc = 1.f, sh = 0.f;
            if (d.bn) {
                float g = d.bn[o], be = d.bn[d.O + o], m = d.bn[2 * d.O + o], v = d.bn[3 * d.O + o];
                sc = g * rsqrtf(v + EPS_BN); sh = be - m * sc;
            }
            d.shb[o] = d.b[o] * sc + sh;
        }
        return;
    } else if (bx < 169) {
        int e = (bx - 96) * 256 + tid;
        if (e < 128 * 144) {
            int k = e / 144, o = e - (e / 144) * 144;
            float sc = a.bn3[o] * rsqrtf(a.bn3[3 * 144 + o] + EPS_BN);
            float s = 0.f;
            for (int c = 0; c < 144; ++c)
                s += a.a2w[c * 128 + k] * a.w3[(size_t)o * 288 + 144 + c];
            a.w3c[k * 144 + o] = s * sc;
        } else if (e < 128 * 144 + 144) {
            int o = e - 128 * 144;
            float g = a.bn3[o], be = a.bn3[144 + o], m = a.bn3[2 * 144 + o], v = a.bn3[3 * 144 + o];
            float sc = g * rsqrtf(v + EPS_BN);
            float s = 0.f;
            for (int c = 0; c < 144; ++c) s += a.w3[(size_t)o * 288 + 144 + c] * a.a2b[c];
            a.sh3[o] = (s + a.b3[o] - m) * sc + be;
        }
        return;
    } else if (bx < 171) {
        int e = (bx - 169) * 256 + tid;
        if (e < 3 * 72) {
            int k = e / 72, o = e - (e / 72) * 72;
            float sc = a.bn5[o] * rsqrtf(a.bn5[3 * 72 + o] + EPS_BN);
            float s = 0.f;
            for (int c = 0; c < 72; ++c)
                s += a.a1w[c * 3 + k] * a.w5[(size_t)o * 144 + 72 + c];
            a.w5c[k * 72 + o] = s * sc;
        } else if (e < 3 * 72 + 72) {
            int o = e - 3 * 72;
            float g = a.bn5[o], be = a.bn5[72 + o], m = a.bn5[2 * 72 + o], v = a.bn5[3 * 72 + o];
            float sc = g * rsqrtf(v + EPS_BN);
            float s = 0.f;
            for (int c = 0; c < 72; ++c) s += a.w5[(size_t)o * 144 + 72 + c] * a.a1b[c];
            a.sh5[o] = (s + a.b5[o] - m) * sc + be;
        }
        return;
    }
    // ---- three_nn: 256 threads = 32 unknowns x 8 segments ----
    const int NSEG = 8;
    __shared__ float kl[3 * 1024];
    __shared__ float sd[NSEG][32][3];
    __shared__ int   si[NSEG][32][3];
    const float* unknown; const float* known;
    int Nu, Nk, blk, b; int* idx; float* wgt;
    int t = bx - 171;
    if (t < 64) {
        unknown = a.xyz1; known = a.xyz2; Nu = 1024; Nk = 256;
        b = t >> 5; blk = t & 31; idx = a.idx1; wgt = a.wgt1;
    } else {
        t -= 64;
        unknown = a.xyz0; known = a.xyz1; Nu = 4096; Nk = 1024;
        b = t >> 7; blk = t & 127; idx = a.idx2; wgt = a.wgt2;
    }
    for (int i = tid; i < Nk * 3; i += 256) kl[i] = known[(size_t)b * Nk * 3 + i];
    __syncthreads();
    const int u   = tid & 31;
    const int seg = tid >> 5;
    const int n   = blk * 32 + u;
    const float* up = unknown + ((size_t)b * Nu + n) * 3;
    const float ux = up[0], uy = up[1], uz = up[2];
    float d0 = 1e30f, d1 = 1e30f, d2 = 1e30f;
    int i0 = 0, i1 = 0, i2 = 0;
    const int klo = seg * (Nk / NSEG), khi = klo + Nk / NSEG;
    for (int k = klo; k < khi; ++k) {
        float dx = __fsub_rn(ux, kl[3 * k + 0]);
        float dy = __fsub_rn(uy, kl[3 * k + 1]);
        float dz = __fsub_rn(uz, kl[3 * k + 2]);
        float d = __fadd_rn(__fadd_rn(__fmul_rn(dx, dx), __fmul_rn(dy, dy)), __fmul_rn(dz, dz));
        if (d < d0)      { d2 = d1; i2 = i1; d1 = d0; i1 = i0; d0 = d; i0 = k; }
        else if (d < d1) { d2 = d1; i2 = i1; d1 = d;  i1 = k; }
        else if (d < d2) { d2 = d;  i2 = k; }
    }
    sd[seg][u][0] = d0; sd[seg][u][1] = d1; sd[seg][u][2] = d2;
    si[seg][u][0] = i0; si[seg][u][1] = i1; si[seg][u][2] = i2;
    __syncthreads();
    if (tid < 32) {
        float m0 = 1e30f, m1 = 1e30f, m2 = 1e30f;
        int j0 = 0, j1 = 0, j2 = 0;
        for (int s = 0; s < NSEG; ++s)
            for (int c = 0; c < 3; ++c) {
                float d = sd[s][u][c];
                int ii = si[s][u][c];
                if (d < m0)      { m2 = m1; j2 = j1; m1 = m0; j1 = j0; m0 = d; j0 = ii; }
                else if (d < m1) { m2 = m1; j2 = j1; m1 = d;  j1 = ii; }
                else if (d < m2) { m2 = d;  j2 = ii; }
            }
        float w0 = 1.f / (m0 + 1e-8f), w1 = 1.f / (m1 + 1e-8f), w2 = 1.f / (m2 + 1e-8f);
        float s = w0 + w1 + w2;
        size_t base = ((size_t)b * Nu + n) * 3;
        idx[base + 0] = j0; idx[base + 1] = j1; idx[base + 2] = j2;
        wgt[base + 0] = w0 / s; wgt[base + 1] = w1 / s; wgt[base + 2] = w2 / s;
    }
}

// ---------------- conv body: pk-fma, optional transposed ([n][c]) output ----
template <int BLK, int CT, int O, int OT, bool RELU, int ADD, bool TOUT>
__device__ __forceinline__ void conv_body(
    int nt, int ot, int nb, int tid,
    const float* __restrict__ src0, int qdiv0,
    const float* __restrict__ Wt, const float* __restrict__ shb,
    const float* __restrict__ basep, int qdivb,
    float* __restrict__ outp, int N, float* wlds)
{
    static_assert(OT % 4 == 0, "OT float4 grouping");
    static_assert(CT % 8 == 0 || CT % 8 == 4, "CT pipeline tail");
    const int oBase = ot * OT;
    const int n0 = (nt * BLK + tid) * 4;

    for (int i = tid; i < CT * OT; i += BLK)
        wlds[i] = Wt[(size_t)(i / OT) * O + oBase + (i % OT)];
    __syncthreads();

    const float* s0 = src0 + (size_t)(nb / qdiv0) * CT * N + n0;

    v2f acc[OT][2];
#pragma unroll
    for (int ol = 0; ol < OT; ++ol) { acc[ol][0] = (v2f)0.f; acc[ol][1] = (v2f)0.f; }

    auto loadrow = [&](float (&x)[4], int c) {
        float4 t = *reinterpret_cast<const float4*>(s0 + (size_t)c * N);
        x[0] = t.x; x[1] = t.y; x[2] = t.z; x[3] = t.w;
    };
    auto comprow = [&](const float (&x)[4], int c) {
        v2f x01; x01[0] = x[0]; x01[1] = x[1];
        v2f x23; x23[0] = x[2]; x23[1] = x[3];
#pragma unroll
        for (int g = 0; g < OT / 4; ++g) {
            float4 wv = *reinterpret_cast<const float4*>(&wlds[c * OT + g * 4]);
            float ww[4] = {wv.x, wv.y, wv.z, wv.w};
#pragma unroll
            for (int r = 0; r < 4; ++r) {
                v2f w2; w2[0] = ww[r]; w2[1] = ww[r];
                acc[g * 4 + r][0] = __builtin_elementwise_fma(w2, x01, acc[g * 4 + r][0]);
                acc[g * 4 + r][1] = __builtin_elementwise_fma(w2, x23, acc[g * 4 + r][1]);
            }
        }
    };
    auto loadg = [&](float (&buf)[4][4], int c) {
#pragma unroll
        for (int q = 0; q < 4; ++q) loadrow(buf[q], c + q);
    };
    auto compg = [&](const float (&buf)[4][4], int c) {
#pragma unroll
        for (int q = 0; q < 4; ++q) comprow(buf[q], c + q);
    };

    {
        float xa[4][4], xb[4][4];
        loadg(xa, 0); loadg(xb, 4);
        int c = 0;
#pragma unroll 1
        for (; c + 16 <= CT; c += 8) {
            compg(xa, c);     loadg(xa, c + 8);
            compg(xb, c + 4); loadg(xb, c + 12);
        }
        compg(xa, c);
        if constexpr (CT % 8 == 4) {
            loadg(xa, c + 8);
            compg(xb, c + 4);
            compg(xa, c + 8);
        } else {
            compg(xb, c + 4);
        }
    }

    if constexpr (TOUT) {
        // transposed output: out[(nb*N + n)*O + o], OT==4 -> one float4 per n
#pragma unroll
        for (int j = 0; j < 4; ++j) {
            float4 t;
            t.x = acc[0][j >> 1][j & 1];
            t.y = acc[1][j >> 1][j & 1];
            t.z = acc[2][j >> 1][j & 1];
            t.w = acc[3][j >> 1][j & 1];
            *reinterpret_cast<float4*>(outp + ((size_t)nb * N + n0 + j) * O + oBase) = t;
        }
        return;
    }

    const float* bp = (ADD == 2) ? (basep + ((size_t)(nb / qdivb) * O + oBase) * N + n0) : nullptr;
#pragma unroll
    for (int ol = 0; ol < OT; ++ol) {
        int o = oBase + ol;
        float addv[4];
        if constexpr (ADD == 2) {
            float4 t = *reinterpret_cast<const float4*>(bp + (size_t)ol * N);
            addv[0] = t.x; addv[1] = t.y; addv[2] = t.z; addv[3] = t.w;
        } else if constexpr (ADD == 1) {
            float sb = shb[o];
#pragma unroll
            for (int j = 0; j < 4; ++j) addv[j] = sb;
        } else {
#pragma unroll
            for (int j = 0; j < 4; ++j) addv[j] = 0.f;
        }
        float res[4];
#pragma unroll
        for (int j = 0; j < 4; ++j) {
            float y = acc[ol][j >> 1][j & 1] + addv[j];
            if constexpr (RELU) y = fmaxf(y, 0.f);
            res[j] = y;
        }
        float4 t; t.x = res[0]; t.y = res[1]; t.z = res[2]; t.w = res[3];
        *reinterpret_cast<float4*>(outp + ((size_t)nb * O + o) * N + n0) = t;
    }
}

template <int BLK, int CT, int O, int OT, bool RELU, int ADD, bool TOUT>
__global__ __launch_bounds__(BLK) void conv_swz(
    const float* __restrict__ src0, int qdiv0,
    const float* __restrict__ Wt, const float* __restrict__ shb,
    const float* __restrict__ basep, int qdivb,
    float* __restrict__ outp, int N, int GX, int GY)
{
    __shared__ __align__(16) float wlds[CT * OT];
    int f = blockIdx.x;
    int J = gridDim.x >> 3;
    int j = (f & 7) * J + (f >> 3);
    int ot = j % GY; int r = j / GY;
    int nt = r % GX; int nb = r / GX;
    conv_body<BLK, CT, O, OT, RELU, ADD, TOUT>(
        nt, ot, nb, threadIdx.x, src0, qdiv0, Wt, shb, basep, qdivb, outp, N, wlds);
}

// per-b bases: [0,148)=base1, [148,436)=base3
__global__ __launch_bounds__(64) void bases_kernel(
    const float* __restrict__ x, const float* __restrict__ sa1f,
    const float* __restrict__ wt1, const float* __restrict__ sb1,
    const float* __restrict__ w3c, const float* __restrict__ sh3,
    float* __restrict__ base1, float* __restrict__ base3)
{
    __shared__ __align__(16) float wlds[288 * 4];
    const int bx = blockIdx.x, tid = threadIdx.x;
    if (bx < 148) {
        int ot = bx % 74, nb = bx / 74;
        conv_body<64, 288, 296, 4, false, 1, false>(0, ot, nb, tid, x, 1, wt1, sb1, nullptr, 1, base1, 256, wlds);
    } else {
        int lb = bx - 148;
        int nt = lb % 4, ot = (lb / 4) % 36, nb = lb / 144;
        conv_body<64, 128, 144, 4, false, 1, false>(nt, ot, nb, tid, sa1f, 1, w3c, sh3, nullptr, 1, base3, 1024, wlds);
    }
}

// ---------------- gather1: contiguous column reads from g3t [n][144] --------
__global__ __launch_bounds__(64) void gather_t1_kernel(
    const float* __restrict__ g3t,   // (NB, 256, 144)  n-major
    const int* __restrict__ idx, const float* __restrict__ wgt,  // (B,1024,3)
    const float* __restrict__ base3, // (B, 144, 1024)
    float* __restrict__ h3)          // (NB, 144, 1024)
{
    int f = blockIdx.x;              // 512 blocks
    int j = (f & 7) * 64 + (f >> 3);
    int nb = j >> 4, nt = j & 15;
    int lane = threadIdx.x;
    int n = nt * 64 + lane;
    int b = nb >> 4;
    size_t nn = ((size_t)b * 1024 + n) * 3;
    int j0 = idx[nn], j1 = idx[nn + 1], j2 = idx[nn + 2];
    float w0 = wgt[nn], w1 = wgt[nn + 1], w2 = wgt[nn + 2];
    const float* gbase = g3t + (size_t)nb * 256 * 144;
    const float* p0 = gbase + (size_t)j0 * 144;
    const float* p1 = gbase + (size_t)j1 * 144;
    const float* p2 = gbase + (size_t)j2 * 144;
    const float* bb = base3 + (size_t)b * 144 * 1024 + n;
    float* ob = h3 + (size_t)nb * 144 * 1024 + n;
#pragma unroll 1
    for (int cc = 0; cc < 144; cc += 8) {
        float4 a0 = *reinterpret_cast<const float4*>(p0 + cc);
        float4 a0b = *reinterpret_cast<const float4*>(p0 + cc + 4);
        float4 a1 = *reinterpret_cast<const float4*>(p1 + cc);
        float4 a1b = *reinterpret_cast<const float4*>(p1 + cc + 4);
        float4 a2 = *reinterpret_cast<const float4*>(p2 + cc);
        float4 a2b = *reinterpret_cast<const float4*>(p2 + cc + 4);
        float r0[8] = {a0.x, a0.y, a0.z, a0.w, a0b.x, a0b.y, a0b.z, a0b.w};
        float r1[8] = {a1.x, a1.y, a1.z, a1.w, a1b.x, a1b.y, a1b.z, a1b.w};
        float r2[8] = {a2.x, a2.y, a2.z, a2.w, a2b.x, a2b.y, a2b.z, a2b.w};
#pragma unroll
        for (int r = 0; r < 8; ++r) {
            float v = w0 * r0[r] + w1 * r1[r] + w2 * r2[r] + bb[(size_t)(cc + r) * 1024];
            ob[(size_t)(cc + r) * 1024] = fmaxf(v, 0.f);
        }
    }
}

// ---------------- fused gather2 + base5 + h6 + out, reads g5t [n][72] -------
__global__ __launch_bounds__(64) void h6out_kernel(
    const float* __restrict__ g5t,   // (NB, 1024, 72)  n-major
    const int* __restrict__ idx, const float* __restrict__ wgt,  // (B,4096,3)
    const float* __restrict__ sa0,   // (B, 3, 4096)
    const float* __restrict__ w5c, const float* __restrict__ sh5,
    const float* __restrict__ Wt6, const float* __restrict__ shb6,
    const float* __restrict__ wout, const float* __restrict__ bout,
    float* __restrict__ outp)        // (NB, 4096)
{
    __shared__ __align__(16) float wlds[72 * 36];
    __shared__ float w5l[3 * 72];
    __shared__ float sh5l[72], ow[36], sh6l[36];
    const int tid = threadIdx.x;
    for (int i = tid; i < 72 * 36; i += 64) wlds[i] = Wt6[i];
    for (int i = tid; i < 216; i += 64) w5l[i] = w5c[i];
    for (int i = tid; i < 72; i += 64) sh5l[i] = sh5[i];
    if (tid < 36) { ow[tid] = wout[tid]; sh6l[tid] = shb6[tid]; }
    __syncthreads();
    int f = blockIdx.x;
    int j = (f & 7) * ((int)gridDim.x >> 3) + (f >> 3);
    const int nb = j >> 6;
    const int nt = j & 63;
    const int n = nt * 64 + tid;
    const int b = nb >> 4;
    size_t nn = ((size_t)b * 4096 + n) * 3;
    const int j0 = idx[nn], j1 = idx[nn + 1], j2 = idx[nn + 2];
    const float w0 = wgt[nn], w1 = wgt[nn + 1], w2 = wgt[nn + 2];
    const float* gbase = g5t + (size_t)nb * 1024 * 72;
    const float* p0 = gbase + (size_t)j0 * 72;
    const float* p1 = gbase + (size_t)j1 * 72;
    const float* p2 = gbase + (size_t)j2 * 72;
    const float* s0 = sa0 + (size_t)b * 3 * 4096 + n;
    const float sx = s0[0], sy = s0[4096], sz = s0[8192];

    v2f acc[18];
#pragma unroll
    for (int o = 0; o < 18; ++o) acc[o] = (v2f)0.f;

    float ra[8][3], rb[8][3];
    auto ld = [&](float (&r)[8][3], int c) {
        float4 a0 = *reinterpret_cast<const float4*>(p0 + c);
        float4 a0b = *reinterpret_cast<const float4*>(p0 + c + 4);
        float4 a1 = *reinterpret_cast<const float4*>(p1 + c);
        float4 a1b = *reinterpret_cast<const float4*>(p1 + c + 4);
        float4 a2 = *reinterpret_cast<const float4*>(p2 + c);
        float4 a2b = *reinterpret_cast<const float4*>(p2 + c + 4);
        r[0][0] = a0.x; r[1][0] = a0.y; r[2][0] = a0.z; r[3][0] = a0.w;
        r[4][0] = a0b.x; r[5][0] = a0b.y; r[6][0] = a0b.z; r[7][0] = a0b.w;
        r[0][1] = a1.x; r[1][1] = a1.y; r[2][1] = a1.z; r[3][1] = a1.w;
        r[4][1] = a1b.x; r[5][1] = a1b.y; r[6][1] = a1b.z; r[7][1] = a1b.w;
        r[0][2] = a2.x; r[1][2] = a2.y; r[2][2] = a2.z; r[3][2] = a2.w;
        r[4][2] = a2b.x; r[5][2] = a2b.y; r[6][2] = a2b.z; r[7][2] = a2b.w;
    };
    auto cp = [&](const float (&r)[8][3], int c) {
#pragma unroll
        for (int q = 0; q < 8; ++q) {
            int cc = c + q;
            float base = w5l[cc] * sx + w5l[72 + cc] * sy + w5l[144 + cc] * sz + sh5l[cc];
            float xv = fmaxf(w0 * r[q][0] + w1 * r[q][1] + w2 * r[q][2] + base, 0.f);
            v2f xv2; xv2[0] = xv; xv2[1] = xv;
#pragma unroll
            for (int g = 0; g < 9; ++g) {
                float4 wv = *reinterpret_cast<const float4*>(&wlds[cc * 36 + g * 4]);
                v2f wa; wa[0] = wv.x; wa[1] = wv.y;
                v2f wb; wb[0] = wv.z; wb[1] = wv.w;
                acc[g * 2 + 0] = __builtin_elementwise_fma(wa, xv2, acc[g * 2 + 0]);
                acc[g * 2 + 1] = __builtin_elementwise_fma(wb, xv2, acc[g * 2 + 1]);
            }
        }
    };
    ld(ra, 0); ld(rb, 8);
    int c = 0;
#pragma unroll 1
    for (; c + 32 <= 72; c += 16) {
        cp(ra, c);     ld(ra, c + 16);
        cp(rb, c + 8); ld(rb, c + 24);
    }
    // c == 48: chunks 48(ra), 56(rb), 64 remain
    cp(ra, 48); ld(ra, 64);
    cp(rb, 56);
    cp(ra, 64);

    float r = bout[0];
#pragma unroll
    for (int o = 0; o < 36; ++o) r += ow[o] * fmaxf(acc[o >> 1][o & 1] + sh6l[o], 0.f);
    outp[(size_t)nb * 4096 + n] = r;
}

extern "C" void kernel_launch(void* const* d_in, const int* in_sizes, int n_in,
                              void* d_out, int out_size, void* d_ws, size_t ws_size,
                              hipStream_t stream) {
    const int B = 2, Q = 16, N0 = 4096, N1 = 1024, N2 = 256;
    const int I1 = 144;
    const int NB = B * Q;  // 32

    const float* x     = (const float*)d_in[0];
    const float* mask  = (const float*)d_in[1];
    const float* sa0f  = (const float*)d_in[2];
    const float* sa1f  = (const float*)d_in[3];
    const float* xyz0  = (const float*)d_in[4];
    const float* xyz1  = (const float*)d_in[5];
    const float* xyz2  = (const float*)d_in[6];

    float* ws = (float*)d_ws;
    size_t off = 0;
    auto alloc = [&](size_t n) { size_t p = off; off += (n + 15) & ~(size_t)15; return p; };

    size_t wgt1  = alloc((size_t)B * N1 * 3);
    size_t wgt2  = alloc((size_t)B * N0 * 3);
    size_t idx1  = alloc((size_t)B * N1 * 3);
    size_t idx2  = alloc((size_t)B * N0 * 3);
    size_t slotA = alloc((size_t)NB * 296 * N2);  // h1 / g3t / h4
    size_t slotB = alloc((size_t)NB * I1 * N1);   // h2 / h3 / g5t
    size_t base1 = alloc((size_t)B * 296 * N2);
    size_t base3 = alloc((size_t)B * I1 * N1);
    size_t wt1 = alloc(296 * 296), sb1 = alloc(296);
    size_t wt2 = alloc(296 * 144), sb2 = alloc(144);
    size_t wt3 = alloc(288 * 144), sb3 = alloc(144);
    size_t wt4 = alloc(144 * 72),  sb4 = alloc(72);
    size_t wt5 = alloc(144 * 72),  sb5 = alloc(72);
    size_t wt6 = alloc(72 * 36),   sb6 = alloc(36);
    size_t w3c = alloc(128 * 144), sh3 = alloc(144);
    size_t w5c = alloc(3 * 72),    sh5 = alloc(72);
    (void)ws_size; (void)in_sizes; (void)n_in;

    auto din = [&](int i) { return (const float*)d_in[i]; };

    HeadArgs ha;
    ha.l[0] = { din(7),  din(8),  din(9),  ws + wt1, ws + sb1, 296, 296 };
    ha.l[1] = { din(10), din(11), din(12), ws + wt2, ws + sb2, 144, 296 };
    ha.l[2] = { din(17), din(18), din(19), ws + wt3, ws + sb3, 144, 288 };
    ha.l[3] = { din(20), din(21), din(22), ws + wt4, ws + sb4, 72, 144 };
    ha.l[4] = { din(23), din(24), din(25), ws + wt5, ws + sb5, 72, 144 };
    ha.l[5] = { din(26), din(27), din(28), ws + wt6, ws + sb6, 36, 72 };
    ha.a2w = din(15); ha.a2b = din(16); ha.w3 = din(17); ha.b3 = din(18); ha.bn3 = din(19);
    ha.w3c = ws + w3c; ha.sh3 = ws + sh3;
    ha.a1w = din(13); ha.a1b = din(14); ha.w5 = din(23); ha.b5 = din(24); ha.bn5 = din(25);
    ha.w5c = ws + w5c; ha.sh5 = ws + sh5;
    ha.xyz0 = xyz0; ha.xyz1 = xyz1; ha.xyz2 = xyz2;
    ha.idx1 = (int*)(ws + idx1); ha.wgt1 = ws + wgt1;
    ha.idx2 = (int*)(ws + idx2); ha.wgt2 = ws + wgt2;
    head_kernel<<<dim3(171 + 64 + 256), 256, 0, stream>>>(ha);

    // per-b bases (base1 | base3)
    bases_kernel<<<dim3(436), 64, 0, stream>>>(
        x, sa1f, ws + wt1, ws + sb1, ws + w3c, ws + sh3, ws + base1, ws + base3);

    // h1 = ReLU(W1[:,288:] @ mask + base1) -> slotA   [2368 blocks]
    conv_swz<64, 8, 296, 4, true, 2, false><<<dim3(2368), 64, 0, stream>>>(
        mask, 1, ws + wt1 + 288 * 296, ws + sb1, ws + base1, Q, ws + slotA, N2, 1, 74);

    // h2 = layer2(h1) -> slotB   [1152 blocks]
    conv_swz<64, 296, 144, 4, true, 1, false><<<dim3(1152), 64, 0, stream>>>(
        ws + slotA, 1, ws + wt2, ws + sb2, nullptr, 1, ws + slotB, N2, 1, 36);

    // g3t = (W3a @ h2)^T  (NB, 256, 144) -> slotA   [1152 blocks]
    conv_swz<64, 144, 144, 4, false, 0, true><<<dim3(1152), 64, 0, stream>>>(
        ws + slotB, 1, ws + wt3, ws + sb3, nullptr, 1, ws + slotA, N2, 1, 36);

    // h3 = ReLU(gather(g3t) + base3) -> slotB   [512 blocks]
    gather_t1_kernel<<<dim3(512), 64, 0, stream>>>(
        ws + slotA, (const int*)(ws + idx1), ws + wgt1, ws + base3, ws + slotB);

    // h4 = ReLU(W4 @ h3 + shb4) -> slotA   [2304 blocks]
    conv_swz<64, 144, 72, 4, true, 1, false><<<dim3(2304), 64, 0, stream>>>(
        ws + slotB, 1, ws + wt4, ws + sb4, nullptr, 1, ws + slotA, N1, 4, 18);

    // g5t = (W5a @ h4)^T  (NB, 1024, 72) -> slotB   [2304 blocks]
    conv_swz<64, 72, 72, 4, false, 0, true><<<dim3(2304), 64, 0, stream>>>(
        ws + slotA, 1, ws + wt5, ws + sb5, nullptr, 1, ws + slotB, N1, 4, 18);

    // fused gather2 + base5 + h6 + out -> d_out   [2048 blocks]
    h6out_kernel<<<dim3(2048), 64, 0, stream>>>(
        ws + slotB, (const int*)(ws + idx2), ws + wgt2, sa0f,
        ws + w5c, ws + sh5, ws + wt6, ws + sb6, din(29), din(30), (float*)d_out);
}